// Round 1
// 410.745 us; speedup vs baseline: 1.0183x; 1.0183x over previous
//
#include <hip/hip_runtime.h>

// Trilinear 3D warp: image [1,1,256,256,256] f32, dvf [1,3,256,256,256] f32
// dvf channels: 0=dy, 1=dx, 2=dz. Layout (H,W,D), D innermost.
//
// R1 (prev): fused z-pair gather (z0, z1=z0+1) into one float2 load.
// R2 (this): wave-level 3D tiling. Lanes of a wave cover a 16(z) x 4(x)
// tile, 4 waves stack in y -> block tile = 4y x 4x x 16z. With dvf ~N(0,1),
// per-lane jitter is +/-2 cells, so lanes now SHARE jittered (y0,x0) columns
// and 16-float z-windows: distinct 64B-line requests per gather drop from
// ~64/wave toward ~50/wave, and the 4 corner gathers + neighbor waves re-hit
// lines in L1. dvf loads / stores stay 4x64B segments per wave (same
// transaction count as fully linear access).

constexpr int H = 256, W = 256, D = 256;
constexpr int N = H * W * D;

__global__ __launch_bounds__(256) void warp3d_kernel(
    const float* __restrict__ img,
    const float* __restrict__ dvf,
    float* __restrict__ out)
{
    // lane -> (z,x), wave -> y
    const int t  = threadIdx.x;
    const int zt = t & 15;          // 16 z per wave
    const int xt = (t >> 4) & 3;    // 4 x per wave
    const int yt = t >> 6;          // wave id = y within tile

    // block -> tile origin; x-tiles fastest so (x,y)-adjacent tiles (which
    // share halo columns) are close in dispatch order for L2 locality.
    const int b  = blockIdx.x;
    const int bx = b & 63;          // 64 x-tiles
    const int by = (b >> 6) & 63;   // 64 y-tiles
    const int bz = b >> 12;         // 16 z-tiles

    const int z = (bz << 4) + zt;
    const int x = (bx << 2) + xt;
    const int y = (by << 2) + yt;

    const int i = (y << 16) | (x << 8) | z;   // (y*W + x)*D + z, dims all 256

    // dvf stream loads (4x64B segments per wave per plane)
    const float dy = dvf[i];
    const float dx = dvf[i + N];
    const float dz = dvf[i + 2 * N];

    const float ny = (float)y + dy;
    const float nx = (float)x + dx;
    const float nz = (float)z + dz;

    const int iy = (int)floorf(ny);
    const int ix = (int)floorf(nx);
    const int iz = (int)floorf(nz);

    const int y0 = min(max(iy,     0), H - 1);
    const int y1 = min(max(iy + 1, 0), H - 1);
    const int x0 = min(max(ix,     0), W - 1);
    const int x1 = min(max(ix + 1, 0), W - 1);
    const int z0 = min(max(iz,     0), D - 1);
    const int z1 = min(max(iz + 1, 0), D - 1);

    // fractions use the CLIPPED low corner (matches reference exactly)
    const float yd = ny - (float)y0;
    const float xd = nx - (float)x0;
    const float zd = nz - (float)z0;

    const int zb = min(z0, D - 2);
    const bool lo = (z0 == zb);       // low corner is v.x
    const bool hi = (z1 == zb + 1);   // high corner is v.y

    const int r00 = (y0 * W + x0) * D + zb;
    const int r01 = (y0 * W + x1) * D + zb;
    const int r10 = (y1 * W + x0) * D + zb;
    const int r11 = (y1 * W + x1) * D + zb;

    // one 8B gather per corner column (4B-aligned; gfx950 handles unaligned)
    const float2 v00 = *reinterpret_cast<const float2*>(img + r00);
    const float2 v01 = *reinterpret_cast<const float2*>(img + r01);
    const float2 v10 = *reinterpret_cast<const float2*>(img + r10);
    const float2 v11 = *reinterpret_cast<const float2*>(img + r11);

    const float c000 = lo ? v00.x : v00.y;
    const float c001 = hi ? v00.y : v00.x;
    const float c010 = lo ? v01.x : v01.y;
    const float c011 = hi ? v01.y : v01.x;
    const float c100 = lo ? v10.x : v10.y;
    const float c101 = hi ? v10.y : v10.x;
    const float c110 = lo ? v11.x : v11.y;
    const float c111 = hi ? v11.y : v11.x;

    const float omz = 1.0f - zd;
    const float c00 = c000 * omz + c001 * zd;
    const float c01 = c010 * omz + c011 * zd;
    const float c10 = c100 * omz + c101 * zd;
    const float c11 = c110 * omz + c111 * zd;

    const float omx = 1.0f - xd;
    const float c0 = c00 * omx + c01 * xd;
    const float c1 = c10 * omx + c11 * xd;

    out[i] = c0 * (1.0f - yd) + c1 * yd;
}

extern "C" void kernel_launch(void* const* d_in, const int* in_sizes, int n_in,
                              void* d_out, int out_size, void* d_ws, size_t ws_size,
                              hipStream_t stream) {
    const float* img = (const float*)d_in[0];
    const float* dvf = (const float*)d_in[1];
    float* out = (float*)d_out;

    dim3 block(256);
    dim3 grid(N / 256);   // 65536 tiles of 4y x 4x x 16z
    warp3d_kernel<<<grid, block, 0, stream>>>(img, dvf, out);
}

// Round 3
// 392.218 us; speedup vs baseline: 1.0664x; 1.0472x over previous
//
#include <hip/hip_runtime.h>

// Trilinear 3D warp: image [1,1,256,256,256] f32, dvf [1,3,256,256,256] f32
// dvf channels: 0=dy, 1=dx, 2=dz. Layout (H,W,D), D innermost.
//
// R1: fused z-pair gather (z0, z1=z0+1) into one float2 load.
// R2: wave-level 3D tiling (wave = 16z x 4x, block = 4y x 4x x 16z).
// R3 (resubmit after infra failure):
//   (a) schedule order bz FASTEST: a 64B image line (16 floats) is exactly
//       one z-tile's window; the +/-1-line z-halo is re-read by the z-adjacent
//       tile, which is now 1 block away (was 4096) -> L2 hit instead of HBM.
//       x-halo neighbor = 16 blocks, y-halo = 1024 blocks (L2/L3).
//   (b) XCD-contiguous chunking: logical index = (orig&7)*8192 + (orig>>3)
//       undoes the round-robin XCD dispatch so logically-adjacent blocks
//       share the same per-XCD L2 (halo lines live in the right cache).
//       65536 % 8 == 0 -> bijective.
//   (c) non-temporal dvf loads + out store: these are pure single-touch
//       streams (each 64B line is read/written by exactly one wave); NT stops
//       them from evicting image halo lines out of L2/L3.

constexpr int H = 256, W = 256, D = 256;
constexpr int N = H * W * D;

__global__ __launch_bounds__(256) void warp3d_kernel(
    const float* __restrict__ img,
    const float* __restrict__ dvf,
    float* __restrict__ out)
{
    // lane -> (z,x), wave -> y
    const int t  = threadIdx.x;
    const int zt = t & 15;          // 16 z per wave
    const int xt = (t >> 4) & 3;    // 4 x per wave
    const int yt = t >> 6;          // wave id = y within tile

    // XCD-contiguous remap, then decode with bz fastest.
    const int orig    = blockIdx.x;
    const int logical = (orig & 7) * 8192 + (orig >> 3);
    const int bz = logical & 15;          // 16 z-tiles   (fastest)
    const int bx = (logical >> 4) & 63;   // 64 x-tiles
    const int by = logical >> 10;         // 64 y-tiles   (slowest)

    const int z = (bz << 4) + zt;
    const int x = (bx << 2) + xt;
    const int y = (by << 2) + yt;

    const int i = (y << 16) | (x << 8) | z;   // (y*W + x)*D + z, dims all 256

    // dvf stream loads: single-touch, keep out of cache
    const float dy = __builtin_nontemporal_load(dvf + i);
    const float dx = __builtin_nontemporal_load(dvf + i + N);
    const float dz = __builtin_nontemporal_load(dvf + i + 2 * N);

    const float ny = (float)y + dy;
    const float nx = (float)x + dx;
    const float nz = (float)z + dz;

    const int iy = (int)floorf(ny);
    const int ix = (int)floorf(nx);
    const int iz = (int)floorf(nz);

    const int y0 = min(max(iy,     0), H - 1);
    const int y1 = min(max(iy + 1, 0), H - 1);
    const int x0 = min(max(ix,     0), W - 1);
    const int x1 = min(max(ix + 1, 0), W - 1);
    const int z0 = min(max(iz,     0), D - 1);
    const int z1 = min(max(iz + 1, 0), D - 1);

    // fractions use the CLIPPED low corner (matches reference exactly)
    const float yd = ny - (float)y0;
    const float xd = nx - (float)x0;
    const float zd = nz - (float)z0;

    const int zb = min(z0, D - 2);
    const bool lo = (z0 == zb);       // low corner is v.x
    const bool hi = (z1 == zb + 1);   // high corner is v.y

    const int r00 = (y0 * W + x0) * D + zb;
    const int r01 = (y0 * W + x1) * D + zb;
    const int r10 = (y1 * W + x0) * D + zb;
    const int r11 = (y1 * W + x1) * D + zb;

    // one 8B gather per corner column (4B-aligned; gfx950 handles unaligned)
    const float2 v00 = *reinterpret_cast<const float2*>(img + r00);
    const float2 v01 = *reinterpret_cast<const float2*>(img + r01);
    const float2 v10 = *reinterpret_cast<const float2*>(img + r10);
    const float2 v11 = *reinterpret_cast<const float2*>(img + r11);

    const float c000 = lo ? v00.x : v00.y;
    const float c001 = hi ? v00.y : v00.x;
    const float c010 = lo ? v01.x : v01.y;
    const float c011 = hi ? v01.y : v01.x;
    const float c100 = lo ? v10.x : v10.y;
    const float c101 = hi ? v10.y : v10.x;
    const float c110 = lo ? v11.x : v11.y;
    const float c111 = hi ? v11.y : v11.x;

    const float omz = 1.0f - zd;
    const float c00 = c000 * omz + c001 * zd;
    const float c01 = c010 * omz + c011 * zd;
    const float c10 = c100 * omz + c101 * zd;
    const float c11 = c110 * omz + c111 * zd;

    const float omx = 1.0f - xd;
    const float c0 = c00 * omx + c01 * xd;
    const float c1 = c10 * omx + c11 * xd;

    const float r = c0 * (1.0f - yd) + c1 * yd;
    __builtin_nontemporal_store(r, out + i);
}

extern "C" void kernel_launch(void* const* d_in, const int* in_sizes, int n_in,
                              void* d_out, int out_size, void* d_ws, size_t ws_size,
                              hipStream_t stream) {
    const float* img = (const float*)d_in[0];
    const float* dvf = (const float*)d_in[1];
    float* out = (float*)d_out;

    dim3 block(256);
    dim3 grid(N / 256);   // 65536 tiles of 4y x 4x x 16z
    warp3d_kernel<<<grid, block, 0, stream>>>(img, dvf, out);
}